// Round 1
// baseline (951.341 us; speedup 1.0000x reference)
//
#include <hip/hip_runtime.h>
#include <hip/hip_bf16.h>

typedef unsigned short u16;
typedef __attribute__((ext_vector_type(8))) short bf16x8;
typedef __attribute__((ext_vector_type(4))) float f32x4;

#define NROWS 4092      // 4 * 1023 valid token rows
#define NROWS_PAD 4096
#define DDIM 2048
#define VDIM 32768
#define NCHUNK 512      // 64-wide vocab chunks per row

// ---------- helpers ----------
__device__ __forceinline__ u16 f2bf(float f) {  // RNE fp32 -> bf16
  union { float f; unsigned u; } v; v.f = f;
  unsigned r = v.u + 0x7FFFu + ((v.u >> 16) & 1u);
  return (u16)(r >> 16);
}

__device__ __forceinline__ void gload16(const void* g, void* l) {
  using gp_t = const __attribute__((address_space(1))) unsigned*;
  using lp_t = __attribute__((address_space(3))) unsigned*;
  // LDS flat addr: low 32 bits are the LDS offset (aperture in high bits)
  __builtin_amdgcn_global_load_lds((gp_t)g, (lp_t)(unsigned)(unsigned long long)l,
                                   16, 0, 0);
}

// ---------- kernel 1: chosen ids (padded) + zero accumulators ----------
__global__ void init_k(const int* __restrict__ ids, int* __restrict__ chosen,
                       float* __restrict__ accum) {
  int i = blockIdx.x * 256 + threadIdx.x;
  if (i < NROWS_PAD) {
    int v = -1;
    if (i < NROWS) { int b = i / 1023, t = i % 1023; v = ids[b * 1024 + t + 1]; }
    chosen[i] = v;
  }
  if (i < 2) accum[i] = 0.f;
}

// ---------- kernel 2: h fp32 -> bf16, row-remapped, zero-padded ----------
__global__ void conv_h(const float* __restrict__ hs, u16* __restrict__ hb) {
  int idx = blockIdx.x * 256 + threadIdx.x;   // 2,097,152 threads
  int row = idx >> 9;                          // / (2048/4)
  int c4 = (idx & 511) << 2;
  ushort4 o;
  if (row < NROWS) {
    int b = row / 1023, t = row % 1023;
    float4 v = *(const float4*)(hs + (size_t)((b << 10) + t) * DDIM + c4);
    o = make_ushort4(f2bf(v.x), f2bf(v.y), f2bf(v.z), f2bf(v.w));
  } else {
    o = make_ushort4(0, 0, 0, 0);
  }
  *(ushort4*)(hb + (size_t)row * DDIM + c4) = o;
}

// ---------- kernel 3: W (D x V fp32) -> W^T (V x D bf16) ----------
__global__ void transpose_w(const float* __restrict__ W, u16* __restrict__ WT) {
  __shared__ u16 t[64 * 68];                  // pad 64->68 to break bank conflicts
  int v0 = blockIdx.x << 6, d0 = blockIdx.y << 6;
  int tid = threadIdx.x;
  int vi = (tid & 15) << 2, dl = tid >> 4;     // read: 4 v per thread, 16 d rows/pass
#pragma unroll
  for (int i = 0; i < 4; ++i) {
    int d = dl + (i << 4);
    float4 w = *(const float4*)(W + (size_t)(d0 + d) * VDIM + v0 + vi);
    *(ushort4*)(&t[d * 68 + vi]) = make_ushort4(f2bf(w.x), f2bf(w.y), f2bf(w.z), f2bf(w.w));
  }
  __syncthreads();
  int d2 = (tid & 31) << 1, vb = tid >> 5;     // write: 2 d per thread (ushort2)
#pragma unroll
  for (int i = 0; i < 8; ++i) {
    int v = vb + (i << 3);
    ushort2 o; o.x = t[d2 * 68 + v]; o.y = t[(d2 + 1) * 68 + v];
    *(ushort2*)(WT + (size_t)(v0 + v) * DDIM + d0 + d2) = o;
  }
}

// ---------- kernel 4: bf16 MFMA GEMM + online-LSE partials + chosen gather ----
// A: [4096][2048] bf16 (rows padded with zeros), Bt: [32768][2048] bf16
// partials: [4096][512] float2 (rowmax, sumexp) per 64-col chunk
__global__ __launch_bounds__(256) void gemm_lse(
    const u16* __restrict__ A, const u16* __restrict__ Bt,
    const int* __restrict__ chosen,
    float2* __restrict__ partials, float* __restrict__ chlog) {
  __shared__ u16 sA[128 * 64];
  __shared__ u16 sB[128 * 64];

  const int tid = threadIdx.x;
  const int l = tid & 63;
  const int wid = tid >> 6;
  const int wm = wid >> 1, wn = wid & 1;
  const int ln = l & 15;
  const int g4 = l >> 4;

  // XCD-chunk swizzle (8192 % 8 == 0, bijective) then 8-wide bm supertile
  int bid = blockIdx.x;
  int xb = ((bid & 7) << 10) | (bid >> 3);
  int gg = xb >> 11;            // 0..3
  int r = xb & 2047;
  int bm = (gg << 3) | (r & 7); // 0..31
  int bn = r >> 3;              // 0..255
  const int m0 = bm << 7, n0 = bn << 7;

  const u16* Ab = A + (size_t)m0 * DDIM;
  const u16* Bb = Bt + (size_t)n0 * DDIM;

  // staging: lane l fills LDS bytes seg*1024 + l*16 (linear dest);
  // source pre-permuted so read-side XOR swizzle sees the right data
  const int srow = l >> 3;                          // row within 8-row seg
  const int selem = ((l & 7) ^ (l >> 3)) << 3;      // element offset in 64-elem slice

  f32x4 acc[4][4] = {};

  for (int kt = 0; kt < 32; ++kt) {
    const int k0 = kt << 6;
#pragma unroll
    for (int i = 0; i < 4; ++i) {
      const int seg = (wid << 2) | i;
      const int row = (seg << 3) | srow;
      gload16(Ab + (size_t)row * DDIM + k0 + selem, sA + (seg << 9));
      gload16(Bb + (size_t)row * DDIM + k0 + selem, sB + (seg << 9));
    }
    __syncthreads();   // drains vmcnt (compiler-inserted) + barrier
#pragma unroll
    for (int h = 0; h < 2; ++h) {
      bf16x8 av[4], bv[4];
#pragma unroll
      for (int mi = 0; mi < 4; ++mi) {
        const int rowt = (wm << 6) | (mi << 4) | ln;
        const int kb = ((h << 6) | (g4 << 4)) ^ ((rowt & 7) << 4);
        av[mi] = *(const bf16x8*)((const char*)sA + rowt * 128 + kb);
      }
#pragma unroll
      for (int ni = 0; ni < 4; ++ni) {
        const int rowt = (wn << 6) | (ni << 4) | ln;
        const int kb = ((h << 6) | (g4 << 4)) ^ ((rowt & 7) << 4);
        bv[ni] = *(const bf16x8*)((const char*)sB + rowt * 128 + kb);
      }
#pragma unroll
      for (int mi = 0; mi < 4; ++mi)
#pragma unroll
        for (int ni = 0; ni < 4; ++ni)
          acc[mi][ni] = __builtin_amdgcn_mfma_f32_16x16x32_bf16(
              av[mi], bv[ni], acc[mi][ni], 0, 0, 0);
    }
    __syncthreads();
  }

  // epilogue: per-row (max, sum-exp) over this wave's 64 cols + chosen gather
  // C/D layout (HW-verified): col = lane&15, row = (lane>>4)*4 + reg
  const int chunk = (bn << 1) | wn;
  const int colb = n0 + (wn << 6) + ln;
#pragma unroll
  for (int mi = 0; mi < 4; ++mi) {
#pragma unroll
    for (int rr = 0; rr < 4; ++rr) {
      const int row = m0 + (wm << 6) + (mi << 4) + (g4 << 2) + rr;
      float v0 = acc[mi][0][rr], v1 = acc[mi][1][rr];
      float v2 = acc[mi][2][rr], v3 = acc[mi][3][rr];
      float mx = fmaxf(fmaxf(v0, v1), fmaxf(v2, v3));
#pragma unroll
      for (int o = 1; o < 16; o <<= 1) mx = fmaxf(mx, __shfl_xor(mx, o, 64));
      float s = __expf(v0 - mx) + __expf(v1 - mx) + __expf(v2 - mx) + __expf(v3 - mx);
#pragma unroll
      for (int o = 1; o < 16; o <<= 1) s += __shfl_xor(s, o, 64);
      if (ln == 0) partials[(size_t)row * NCHUNK + chunk] = make_float2(mx, s);
      const int cc = chosen[row];   // -1 on pad rows -> never matches
      if (cc == colb)      chlog[row] = v0;
      if (cc == colb + 16) chlog[row] = v1;
      if (cc == colb + 32) chlog[row] = v2;
      if (cc == colb + 48) chlog[row] = v3;
    }
  }
}

// ---------- kernel 5: combine partials -> lse -> logps -> loss terms ----------
__global__ void reduce_lse(const float2* __restrict__ partials,
                           const float* __restrict__ chlog,
                           const float* __restrict__ oldlp,
                           const int* __restrict__ labels,
                           const float* __restrict__ adv,
                           float* __restrict__ out, float* __restrict__ accum) {
  const int wid = threadIdx.x >> 6, l = threadIdx.x & 63;
  const int row = blockIdx.x * 4 + wid;        // 1023*4 = 4092 exactly
  float M = -INFINITY, S = 0.f;
  for (int c = l; c < NCHUNK; c += 64) {
    float2 p = partials[(size_t)row * NCHUNK + c];
    float Mn = fmaxf(M, p.x);
    S = S * __expf(M - Mn) + p.y * __expf(p.x - Mn);
    M = Mn;
  }
#pragma unroll
  for (int o = 1; o < 64; o <<= 1) {
    float Mo = __shfl_xor(M, o, 64), So = __shfl_xor(S, o, 64);
    float Mn = fmaxf(M, Mo);
    S = S * __expf(M - Mn) + So * __expf(Mo - Mn);
    M = Mn;
  }
  if (l == 0) {
    float lse = M + __logf(S);
    float ptl = chlog[row] - lse;
    out[1 + row] = ptl;
    int b = row / 1023, t = row % 1023;
    float a = adv[b];
    float ratio = __expf(ptl - oldlp[row]);
    float l1 = ratio * a;
    float l2 = fminf(fmaxf(ratio, 0.8f), 1.3f) * a;   // clip(r, 1-0.2, 1+0.3)
    float mk = (float)labels[b * 1024 + t + 1];
    atomicAdd(accum + 0, -fminf(l1, l2) * mk);
    atomicAdd(accum + 1, mk);
  }
}

__global__ void finalize_k(const float* __restrict__ accum, float* __restrict__ out) {
  out[0] = accum[0] / accum[1];
}

// ---------- launch ----------
extern "C" void kernel_launch(void* const* d_in, const int* in_sizes, int n_in,
                              void* d_out, int out_size, void* d_ws, size_t ws_size,
                              hipStream_t stream) {
  const float* hs     = (const float*)d_in[0];   // (4,1024,2048)
  const float* W      = (const float*)d_in[1];   // (2048,32768)
  const int*   ids    = (const int*)d_in[2];     // (4,1024)
  const int*   labels = (const int*)d_in[3];     // (4,1024)
  const float* adv    = (const float*)d_in[4];   // (4,)
  const float* oldlp  = (const float*)d_in[5];   // (4,1023)
  float* out = (float*)d_out;                    // [loss, 4092 x per_token_logps]

  // ws layout (needs ~160.1 MB):
  char* ws = (char*)d_ws;
  u16*    WT       = (u16*)ws;                         // 134,217,728 B
  u16*    hb       = (u16*)(ws + 134217728);           //  16,777,216 B
  float2* partials = (float2*)(ws + 150994944);        //  16,777,216 B
  float*  chlog    = (float*)(ws + 167772160);         //      16,384 B
  int*    chosen   = (int*)(ws + 167788544);           //      16,384 B
  float*  accum    = (float*)(ws + 167804928);         //           8 B

  init_k<<<16, 256, 0, stream>>>(ids, chosen, accum);
  conv_h<<<8192, 256, 0, stream>>>(hs, hb);
  transpose_w<<<dim3(512, 32), 256, 0, stream>>>(W, WT);
  gemm_lse<<<8192, 256, 0, stream>>>(hb, WT, chosen, partials, chlog);
  reduce_lse<<<1023, 256, 0, stream>>>(partials, chlog, oldlp, labels, adv, out, accum);
  finalize_k<<<1, 1, 0, stream>>>(accum, out);
}

// Round 2
// 744.340 us; speedup vs baseline: 1.2781x; 1.2781x over previous
//
#include <hip/hip_runtime.h>
#include <hip/hip_bf16.h>

typedef unsigned short u16;
typedef __attribute__((ext_vector_type(8))) short bf16x8;
typedef __attribute__((ext_vector_type(4))) float f32x4;

#define NROWS 4092      // 4 * 1023 valid token rows
#define NROWS_PAD 4096
#define DDIM 2048
#define VDIM 32768
#define NCHUNK 512      // 64-wide vocab chunks per row

// ---------- helpers ----------
__device__ __forceinline__ u16 f2bf(float f) {  // RNE fp32 -> bf16
  union { float f; unsigned u; } v; v.f = f;
  unsigned r = v.u + 0x7FFFu + ((v.u >> 16) & 1u);
  return (u16)(r >> 16);
}

__device__ __forceinline__ void gload16(const void* g, void* l) {
  using gp_t = const __attribute__((address_space(1))) unsigned*;
  using lp_t = __attribute__((address_space(3))) unsigned*;
  __builtin_amdgcn_global_load_lds((gp_t)g, (lp_t)(unsigned)(unsigned long long)l,
                                   16, 0, 0);
}

#define BAR() __builtin_amdgcn_s_barrier()
#define WAIT_LGKM0() do { asm volatile("s_waitcnt lgkmcnt(0)" ::: "memory"); \
                          __builtin_amdgcn_sched_barrier(0); } while (0)

// ---------- kernel 1: chosen ids (padded) + zero accumulators ----------
__global__ void init_k(const int* __restrict__ ids, int* __restrict__ chosen,
                       float* __restrict__ accum) {
  int i = blockIdx.x * 256 + threadIdx.x;
  if (i < NROWS_PAD) {
    int v = -1;
    if (i < NROWS) { int b = i / 1023, t = i % 1023; v = ids[b * 1024 + t + 1]; }
    chosen[i] = v;
  }
  if (i < 2) accum[i] = 0.f;
}

// ---------- kernel 2: h fp32 -> bf16, row-remapped, zero-padded ----------
__global__ void conv_h(const float* __restrict__ hs, u16* __restrict__ hb) {
  int idx = blockIdx.x * 256 + threadIdx.x;   // 2,097,152 threads
  int row = idx >> 9;
  int c4 = (idx & 511) << 2;
  ushort4 o;
  if (row < NROWS) {
    int b = row / 1023, t = row % 1023;
    float4 v = *(const float4*)(hs + (size_t)((b << 10) + t) * DDIM + c4);
    o = make_ushort4(f2bf(v.x), f2bf(v.y), f2bf(v.z), f2bf(v.w));
  } else {
    o = make_ushort4(0, 0, 0, 0);
  }
  *(ushort4*)(hb + (size_t)row * DDIM + c4) = o;
}

// ---------- kernel 3: W (D x V fp32) -> W^T (V x D bf16) ----------
__global__ void transpose_w(const float* __restrict__ W, u16* __restrict__ WT) {
  __shared__ u16 t[64 * 68];
  int v0 = blockIdx.x << 6, d0 = blockIdx.y << 6;
  int tid = threadIdx.x;
  int vi = (tid & 15) << 2, dl = tid >> 4;
#pragma unroll
  for (int i = 0; i < 4; ++i) {
    int d = dl + (i << 4);
    float4 w = *(const float4*)(W + (size_t)(d0 + d) * VDIM + v0 + vi);
    *(ushort4*)(&t[d * 68 + vi]) = make_ushort4(f2bf(w.x), f2bf(w.y), f2bf(w.z), f2bf(w.w));
  }
  __syncthreads();
  int d2 = (tid & 31) << 1, vb = tid >> 5;
#pragma unroll
  for (int i = 0; i < 8; ++i) {
    int v = vb + (i << 3);
    ushort2 o; o.x = t[d2 * 68 + v]; o.y = t[(d2 + 1) * 68 + v];
    *(ushort2*)(WT + (size_t)(v0 + v) * DDIM + d0 + d2) = o;
  }
}

// ---------- kernel 4: 256x256 8-phase bf16 MFMA GEMM + online-LSE ----------
// A: [4096][2048] bf16 (zero-padded rows), Bt: [32768][2048] bf16
// LDS layout (dynamic 128 KiB): [buf][A/B][half(128 rows)][128 B/row]
// Stage order during tile t: p0 A0(t+1)->c^1, p1 A1(t+1)->c^1,
//   p2 B0(t+2)->c.B, p3 B1(t+2)->c.B  (c.B free after p0's bv reads)
// Tile boundary wait: vmcnt(4) (B(t+2)'s 4 loads stay in flight).
__global__ __launch_bounds__(512, 2) void gemm_lse(
    const u16* __restrict__ A, const u16* __restrict__ Bt,
    const int* __restrict__ chosen,
    float2* __restrict__ partials, float* __restrict__ chlog) {
  extern __shared__ u16 smem[];
  char* lds = (char*)smem;

  const int tid = threadIdx.x;
  const int l = tid & 63;
  const int wid = tid >> 6;          // 8 waves
  const int wm = wid >> 2, wn = wid & 3;   // 2 x 4
  const int ln = l & 15;
  const int g4 = l >> 4;

  // XCD-bijective swizzle (2048 blocks % 8 == 0): each XCD owns 16 bn panels
  int bid = blockIdx.x;
  int id = ((bid & 7) << 8) | (bid >> 3);
  int bm = id & 15;                  // 0..15
  int bn = id >> 4;                  // 0..127
  const int m0 = bm << 8, n0 = bn << 8;

  const u16* Ab = A + (size_t)m0 * DDIM;
  const u16* Bb = Bt + (size_t)n0 * DDIM;

  // staging lane decomposition (linear LDS dest, pre-permuted global source)
  const int srow = l >> 3;
  const int sel = ((l & 7) ^ srow) << 3;

#define STAGE(bufB, abB, halfB, src, tt) do {                                  \
    char* _b = lds + (bufB) * 65536 + (abB) * 32768 + (halfB) * 16384;         \
    _Pragma("unroll")                                                          \
    for (int _j = 0; _j < 2; ++_j) {                                           \
      int _seg = (_j << 3) | wid;                                              \
      int _r = (_seg << 3) | srow;                                             \
      gload16((src) + (size_t)((halfB) * 128 + _r) * DDIM + ((tt) << 6) + sel, \
              _b + (_seg << 10));                                              \
    } } while (0)

#define LDA(buf, arow, h)                                                      \
  (*(const bf16x8*)(lds + (buf) * 65536 + ((arow) >> 7) * 16384 +              \
                    ((arow) & 127) * 128 +                                     \
                    (((((h) << 2) | g4) ^ ((arow) & 7)) << 4)))
#define LDB(buf, brow, h)                                                      \
  (*(const bf16x8*)(lds + (buf) * 65536 + 32768 + ((brow) >> 7) * 16384 +      \
                    ((brow) & 127) * 128 +                                     \
                    (((((h) << 2) | g4) ^ ((brow) & 7)) << 4)))

  f32x4 acc[8][4] = {};

  // prologue: tile0 full -> buf0; B(1) -> buf1.B; wait tile0, leave B(1) in flight
  STAGE(0, 0, 0, Ab, 0); STAGE(0, 0, 1, Ab, 0);
  STAGE(0, 1, 0, Bb, 0); STAGE(0, 1, 1, Bb, 0);
  STAGE(1, 1, 0, Bb, 1); STAGE(1, 1, 1, Bb, 1);
  asm volatile("s_waitcnt vmcnt(4)" ::: "memory");
  BAR();

  for (int t = 0; t < 32; ++t) {
    const int c = t & 1;
    bf16x8 bv[4][2];
    bf16x8 av[2][2];
#pragma unroll
    for (int q = 0; q < 4; ++q) {
      if (q == 0) {
#pragma unroll
        for (int ni = 0; ni < 4; ++ni)
#pragma unroll
          for (int h = 0; h < 2; ++h)
            bv[ni][h] = LDB(c, (wn << 6) + (ni << 4) + ln, h);
      }
#pragma unroll
      for (int i = 0; i < 2; ++i)
#pragma unroll
        for (int h = 0; h < 2; ++h)
          av[i][h] = LDA(c, (wm << 7) + (((q << 1) + i) << 4) + ln, h);
      // stage schedule
      if (q == 0 && t < 31) STAGE(c ^ 1, 0, 0, Ab, t + 1);
      if (q == 1 && t < 31) STAGE(c ^ 1, 0, 1, Ab, t + 1);
      if (q == 2 && t < 30) STAGE(c, 1, 0, Bb, t + 2);
      if (q == 3 && t < 30) STAGE(c, 1, 1, Bb, t + 2);
      BAR();
      WAIT_LGKM0();
      __builtin_amdgcn_s_setprio(1);
#pragma unroll
      for (int h = 0; h < 2; ++h)
#pragma unroll
        for (int i = 0; i < 2; ++i)
#pragma unroll
          for (int ni = 0; ni < 4; ++ni)
            acc[(q << 1) + i][ni] = __builtin_amdgcn_mfma_f32_16x16x32_bf16(
                av[i][h], bv[ni][h], acc[(q << 1) + i][ni], 0, 0, 0);
      __builtin_amdgcn_s_setprio(0);
      if (q == 3) {
        if (t < 30)       { asm volatile("s_waitcnt vmcnt(4)" ::: "memory"); }
        else if (t == 30) { asm volatile("s_waitcnt vmcnt(0)" ::: "memory"); }
      }
      BAR();
    }
  }

  // epilogue: per-row (max, sum-exp) over this wave's 64 cols + chosen gather
  // C/D layout: col = lane&15, row = (lane>>4)*4 + reg
  const int chunk = (bn << 2) | wn;
  const int colb = n0 + (wn << 6) + ln;
#pragma unroll
  for (int mi = 0; mi < 8; ++mi) {
#pragma unroll
    for (int rr = 0; rr < 4; ++rr) {
      const int row = m0 + (wm << 7) + (mi << 4) + (g4 << 2) + rr;
      float v0 = acc[mi][0][rr], v1 = acc[mi][1][rr];
      float v2 = acc[mi][2][rr], v3 = acc[mi][3][rr];
      float mx = fmaxf(fmaxf(v0, v1), fmaxf(v2, v3));
#pragma unroll
      for (int o = 1; o < 16; o <<= 1) mx = fmaxf(mx, __shfl_xor(mx, o, 64));
      float s = __expf(v0 - mx) + __expf(v1 - mx) + __expf(v2 - mx) + __expf(v3 - mx);
#pragma unroll
      for (int o = 1; o < 16; o <<= 1) s += __shfl_xor(s, o, 64);
      if (ln == 0) partials[(size_t)row * NCHUNK + chunk] = make_float2(mx, s);
      const int cc = chosen[row];   // -1 on pad rows -> never matches
      if (cc == colb)      chlog[row] = v0;
      if (cc == colb + 16) chlog[row] = v1;
      if (cc == colb + 32) chlog[row] = v2;
      if (cc == colb + 48) chlog[row] = v3;
    }
  }
#undef STAGE
#undef LDA
#undef LDB
}

// ---------- kernel 5: combine partials -> lse -> logps -> loss terms ----------
__global__ void reduce_lse(const float2* __restrict__ partials,
                           const float* __restrict__ chlog,
                           const float* __restrict__ oldlp,
                           const int* __restrict__ labels,
                           const float* __restrict__ adv,
                           float* __restrict__ out, float* __restrict__ accum) {
  const int wid = threadIdx.x >> 6, l = threadIdx.x & 63;
  const int row = blockIdx.x * 4 + wid;        // 1023*4 = 4092 exactly
  float M = -INFINITY, S = 0.f;
  for (int c = l; c < NCHUNK; c += 64) {
    float2 p = partials[(size_t)row * NCHUNK + c];
    float Mn = fmaxf(M, p.x);
    S = S * __expf(M - Mn) + p.y * __expf(p.x - Mn);
    M = Mn;
  }
#pragma unroll
  for (int o = 1; o < 64; o <<= 1) {
    float Mo = __shfl_xor(M, o, 64), So = __shfl_xor(S, o, 64);
    float Mn = fmaxf(M, Mo);
    S = S * __expf(M - Mn) + So * __expf(Mo - Mn);
    M = Mn;
  }
  if (l == 0) {
    float lse = M + __logf(S);
    float ptl = chlog[row] - lse;
    out[1 + row] = ptl;
    int b = row / 1023, t = row % 1023;
    float a = adv[b];
    float ratio = __expf(ptl - oldlp[row]);
    float l1 = ratio * a;
    float l2 = fminf(fmaxf(ratio, 0.8f), 1.3f) * a;
    float mk = (float)labels[b * 1024 + t + 1];
    atomicAdd(accum + 0, -fminf(l1, l2) * mk);
    atomicAdd(accum + 1, mk);
  }
}

__global__ void finalize_k(const float* __restrict__ accum, float* __restrict__ out) {
  out[0] = accum[0] / accum[1];
}

// ---------- launch ----------
extern "C" void kernel_launch(void* const* d_in, const int* in_sizes, int n_in,
                              void* d_out, int out_size, void* d_ws, size_t ws_size,
                              hipStream_t stream) {
  const float* hs     = (const float*)d_in[0];   // (4,1024,2048)
  const float* W      = (const float*)d_in[1];   // (2048,32768)
  const int*   ids    = (const int*)d_in[2];     // (4,1024)
  const int*   labels = (const int*)d_in[3];     // (4,1024)
  const float* adv    = (const float*)d_in[4];   // (4,)
  const float* oldlp  = (const float*)d_in[5];   // (4,1023)
  float* out = (float*)d_out;                    // [loss, 4092 x per_token_logps]

  char* ws = (char*)d_ws;
  u16*    WT       = (u16*)ws;                         // 134,217,728 B
  u16*    hb       = (u16*)(ws + 134217728);           //  16,777,216 B
  float2* partials = (float2*)(ws + 150994944);        //  16,777,216 B
  float*  chlog    = (float*)(ws + 167772160);         //      16,384 B
  int*    chosen   = (int*)(ws + 167788544);           //      16,384 B
  float*  accum    = (float*)(ws + 167804928);         //           8 B

  (void)hipFuncSetAttribute((const void*)gemm_lse,
                            hipFuncAttributeMaxDynamicSharedMemorySize, 131072);

  init_k<<<16, 256, 0, stream>>>(ids, chosen, accum);
  conv_h<<<8192, 256, 0, stream>>>(hs, hb);
  transpose_w<<<dim3(512, 32), 256, 0, stream>>>(W, WT);
  gemm_lse<<<2048, 512, 131072, stream>>>(hb, WT, chosen, partials, chlog);
  reduce_lse<<<1023, 256, 0, stream>>>(partials, chlog, oldlp, labels, adv, out, accum);
  finalize_k<<<1, 1, 0, stream>>>(accum, out);
}

// Round 3
// 723.051 us; speedup vs baseline: 1.3157x; 1.0294x over previous
//
#include <hip/hip_runtime.h>
#include <hip/hip_bf16.h>

typedef unsigned short u16;
typedef __attribute__((ext_vector_type(8))) short bf16x8;
typedef __attribute__((ext_vector_type(4))) float f32x4;

#define NROWS 4092      // 4 * 1023 valid token rows
#define NROWS_PAD 4096
#define DDIM 2048
#define VDIM 32768
#define NCHUNK 512      // 64-wide vocab chunks per row

// ---------- helpers ----------
__device__ __forceinline__ u16 f2bf(float f) {  // RNE fp32 -> bf16
  union { float f; unsigned u; } v; v.f = f;
  unsigned r = v.u + 0x7FFFu + ((v.u >> 16) & 1u);
  return (u16)(r >> 16);
}

__device__ __forceinline__ void gload16(const void* g, void* l) {
  using gp_t = const __attribute__((address_space(1))) unsigned*;
  using lp_t = __attribute__((address_space(3))) unsigned*;
  __builtin_amdgcn_global_load_lds((gp_t)g, (lp_t)(unsigned)(unsigned long long)l,
                                   16, 0, 0);
}

#define BAR() __builtin_amdgcn_s_barrier()
#define SB()  __builtin_amdgcn_sched_barrier(0)
#define WAITLG0() do { asm volatile("s_waitcnt lgkmcnt(0)" ::: "memory"); SB(); } while (0)

// ---------- kernel 1: chosen ids (padded) + zero accumulators ----------
__global__ void init_k(const int* __restrict__ ids, int* __restrict__ chosen,
                       float* __restrict__ accum) {
  int i = blockIdx.x * 256 + threadIdx.x;
  if (i < NROWS_PAD) {
    int v = -1;
    if (i < NROWS) { int b = i / 1023, t = i % 1023; v = ids[b * 1024 + t + 1]; }
    chosen[i] = v;
  }
  if (i < 2) accum[i] = 0.f;
}

// ---------- kernel 2: h fp32 -> bf16, row-remapped, zero-padded ----------
__global__ void conv_h(const float* __restrict__ hs, u16* __restrict__ hb) {
  int idx = blockIdx.x * 256 + threadIdx.x;   // 2,097,152 threads
  int row = idx >> 9;
  int c4 = (idx & 511) << 2;
  ushort4 o;
  if (row < NROWS) {
    int b = row / 1023, t = row % 1023;
    float4 v = *(const float4*)(hs + (size_t)((b << 10) + t) * DDIM + c4);
    o = make_ushort4(f2bf(v.x), f2bf(v.y), f2bf(v.z), f2bf(v.w));
  } else {
    o = make_ushort4(0, 0, 0, 0);
  }
  *(ushort4*)(hb + (size_t)row * DDIM + c4) = o;
}

// ---------- kernel 3: W (D x V fp32) -> W^T (V x D bf16) ----------
__global__ void transpose_w(const float* __restrict__ W, u16* __restrict__ WT) {
  __shared__ u16 t[64 * 68];
  int v0 = blockIdx.x << 6, d0 = blockIdx.y << 6;
  int tid = threadIdx.x;
  int vi = (tid & 15) << 2, dl = tid >> 4;
#pragma unroll
  for (int i = 0; i < 4; ++i) {
    int d = dl + (i << 4);
    float4 w = *(const float4*)(W + (size_t)(d0 + d) * VDIM + v0 + vi);
    *(ushort4*)(&t[d * 68 + vi]) = make_ushort4(f2bf(w.x), f2bf(w.y), f2bf(w.z), f2bf(w.w));
  }
  __syncthreads();
  int d2 = (tid & 31) << 1, vb = tid >> 5;
#pragma unroll
  for (int i = 0; i < 8; ++i) {
    int v = vb + (i << 3);
    ushort2 o; o.x = t[d2 * 68 + v]; o.y = t[(d2 + 1) * 68 + v];
    *(ushort2*)(WT + (size_t)(v0 + v) * DDIM + d0 + d2) = o;
  }
}

// ---------- kernel 4: 256x256 pipelined bf16 MFMA GEMM + online-LSE --------
// A: [4096][2048] bf16 (zero-padded rows), Bt: [32768][2048] bf16
// LDS (dynamic 128 KiB): [buf][A/B][half(128 rows)][128 B/row], XOR-swizzled
// reads with pre-permuted global sources (linear global_load_lds dest).
// Pipeline: fragment ds_reads issued one phase ahead (overlap LDS pipe with
// matrix pipe); 2 barriers/tile (mid-tile protects B-space overwrite,
// boundary after counted vmcnt flips the double buffer).
__global__ __launch_bounds__(512, 2) void gemm_lse(
    const u16* __restrict__ A, const u16* __restrict__ Bt,
    const int* __restrict__ chosen,
    float2* __restrict__ partials, float* __restrict__ chlog) {
  extern __shared__ u16 smem[];
  char* lds = (char*)smem;

  const int tid = threadIdx.x;
  const int l = tid & 63;
  const int wid = tid >> 6;          // 8 waves
  const int wm = wid >> 2, wn = wid & 3;   // 2 x 4
  const int ln = l & 15;
  const int g4 = l >> 4;

  // XCD-bijective swizzle (2048 blocks % 8 == 0): each XCD owns 16 bn panels
  int bid = blockIdx.x;
  int id = ((bid & 7) << 8) | (bid >> 3);
  int bm = id & 15;                  // 0..15
  int bn = id >> 4;                  // 0..127
  const int m0 = bm << 8, n0 = bn << 8;

  const u16* Ab = A + (size_t)m0 * DDIM;
  const u16* Bb = Bt + (size_t)n0 * DDIM;

  // staging lane decomposition (linear LDS dest, pre-permuted global source)
  const int srow = l >> 3;
  const int sel = ((l & 7) ^ srow) << 3;

#define STAGE(bufB, abB, halfB, src, tt) do {                                  \
    char* _b = lds + (bufB) * 65536 + (abB) * 32768 + (halfB) * 16384;         \
    _Pragma("unroll")                                                          \
    for (int _j = 0; _j < 2; ++_j) {                                           \
      int _seg = (_j << 3) | wid;                                              \
      int _r = (_seg << 3) | srow;                                             \
      gload16((src) + (size_t)((halfB) * 128 + _r) * DDIM + ((tt) << 6) + sel, \
              _b + (_seg << 10));                                              \
    } } while (0)

#define LDA(buf, arow, h)                                                      \
  (*(const bf16x8*)(lds + (buf) * 65536 + ((arow) >> 7) * 16384 +              \
                    ((arow) & 127) * 128 +                                     \
                    (((((h) << 2) | g4) ^ ((arow) & 7)) << 4)))
#define LDB(buf, brow, h)                                                      \
  (*(const bf16x8*)(lds + (buf) * 65536 + 32768 + ((brow) >> 7) * 16384 +      \
                    ((brow) & 127) * 128 +                                     \
                    (((((h) << 2) | g4) ^ ((brow) & 7)) << 4)))

#define LOADAV(dst, c, q) do {                                                 \
    _Pragma("unroll")                                                          \
    for (int _i = 0; _i < 2; ++_i)                                             \
      _Pragma("unroll")                                                        \
      for (int _h = 0; _h < 2; ++_h)                                           \
        dst[_i][_h] = LDA(c, (wm << 7) + (((((q) << 1)) + _i) << 4) + ln, _h); \
  } while (0)

#define MFMA_Q(av, q) do {                                                     \
    __builtin_amdgcn_s_setprio(1);                                             \
    _Pragma("unroll")                                                          \
    for (int _h = 0; _h < 2; ++_h)                                             \
      _Pragma("unroll")                                                        \
      for (int _i = 0; _i < 2; ++_i)                                           \
        _Pragma("unroll")                                                      \
        for (int _ni = 0; _ni < 4; ++_ni)                                      \
          acc[((q) << 1) + _i][_ni] = __builtin_amdgcn_mfma_f32_16x16x32_bf16( \
              (av)[_i][_h], bv[_ni][_h], acc[((q) << 1) + _i][_ni], 0, 0, 0);  \
    __builtin_amdgcn_s_setprio(0);                                             \
  } while (0)

  f32x4 acc[8][4] = {};

  // prologue: tile0 full -> buf0; B(1) -> buf1.B; wait tile0, leave B(1) in flight
  STAGE(0, 0, 0, Ab, 0); STAGE(0, 0, 1, Ab, 0);
  STAGE(0, 1, 0, Bb, 0); STAGE(0, 1, 1, Bb, 0);
  STAGE(1, 1, 0, Bb, 1); STAGE(1, 1, 1, Bb, 1);
  asm volatile("s_waitcnt vmcnt(4)" ::: "memory");
  BAR();

  for (int t = 0; t < 32; ++t) {
    const int c = t & 1;
    bf16x8 bv[4][2], avA[2][2], avB[2][2];
    // ---- q0: burst-load bv + av(q0); prefetch av(q1) under MFMA q0
#pragma unroll
    for (int ni = 0; ni < 4; ++ni)
#pragma unroll
      for (int h = 0; h < 2; ++h)
        bv[ni][h] = LDB(c, (wn << 6) + (ni << 4) + ln, h);
    LOADAV(avA, c, 0);
    SB();
    if (t < 31) STAGE(c ^ 1, 0, 0, Ab, t + 1);
    WAITLG0();                 // bv + avA ready
    LOADAV(avB, c, 1);
    SB();
    MFMA_Q(avA, 0);
    // ---- q1
    if (t < 31) STAGE(c ^ 1, 0, 1, Ab, t + 1);
    WAITLG0();                 // avB ready
    LOADAV(avA, c, 2);
    SB();
    MFMA_Q(avB, 1);
    BAR();   // mid-tile: every wave's bv is in regs -> B-space writable
    // ---- q2
    if (t < 30) STAGE(c, 1, 0, Bb, t + 2);
    WAITLG0();                 // avA(q2) ready
    LOADAV(avB, c, 3);
    SB();
    MFMA_Q(avA, 2);
    // ---- q3
    if (t < 30) STAGE(c, 1, 1, Bb, t + 2);
    WAITLG0();                 // avB(q3) ready
    MFMA_Q(avB, 3);
    if (t < 30)       { asm volatile("s_waitcnt vmcnt(4)" ::: "memory"); }
    else if (t == 30) { asm volatile("s_waitcnt vmcnt(0)" ::: "memory"); }
    SB();
    BAR();   // tile boundary: staged tile t+1 globally visible, flip buffer
  }

  // epilogue: per-row (max, sum-exp) over this wave's 64 cols + chosen gather
  // C/D layout: col = lane&15, row = (lane>>4)*4 + reg
  const int chunk = (bn << 2) | wn;
  const int colb = n0 + (wn << 6) + ln;
#pragma unroll
  for (int mi = 0; mi < 8; ++mi) {
#pragma unroll
    for (int rr = 0; rr < 4; ++rr) {
      const int row = m0 + (wm << 7) + (mi << 4) + (g4 << 2) + rr;
      float v0 = acc[mi][0][rr], v1 = acc[mi][1][rr];
      float v2 = acc[mi][2][rr], v3 = acc[mi][3][rr];
      float mx = fmaxf(fmaxf(v0, v1), fmaxf(v2, v3));
#pragma unroll
      for (int o = 1; o < 16; o <<= 1) mx = fmaxf(mx, __shfl_xor(mx, o, 64));
      float s = __expf(v0 - mx) + __expf(v1 - mx) + __expf(v2 - mx) + __expf(v3 - mx);
#pragma unroll
      for (int o = 1; o < 16; o <<= 1) s += __shfl_xor(s, o, 64);
      if (ln == 0) partials[(size_t)row * NCHUNK + chunk] = make_float2(mx, s);
      const int cc = chosen[row];   // -1 on pad rows -> never matches
      if (cc == colb)      chlog[row] = v0;
      if (cc == colb + 16) chlog[row] = v1;
      if (cc == colb + 32) chlog[row] = v2;
      if (cc == colb + 48) chlog[row] = v3;
    }
  }
#undef STAGE
#undef LDA
#undef LDB
#undef LOADAV
#undef MFMA_Q
}

// ---------- kernel 5: combine partials -> lse -> logps -> loss terms ----------
__global__ void reduce_lse(const float2* __restrict__ partials,
                           const float* __restrict__ chlog,
                           const float* __restrict__ oldlp,
                           const int* __restrict__ labels,
                           const float* __restrict__ adv,
                           float* __restrict__ out, float* __restrict__ accum) {
  const int wid = threadIdx.x >> 6, l = threadIdx.x & 63;
  const int row = blockIdx.x * 4 + wid;        // 1023*4 = 4092 exactly
  float M = -INFINITY, S = 0.f;
  for (int c = l; c < NCHUNK; c += 64) {
    float2 p = partials[(size_t)row * NCHUNK + c];
    float Mn = fmaxf(M, p.x);
    S = S * __expf(M - Mn) + p.y * __expf(p.x - Mn);
    M = Mn;
  }
#pragma unroll
  for (int o = 1; o < 64; o <<= 1) {
    float Mo = __shfl_xor(M, o, 64), So = __shfl_xor(S, o, 64);
    float Mn = fmaxf(M, Mo);
    S = S * __expf(M - Mn) + So * __expf(Mo - Mn);
    M = Mn;
  }
  if (l == 0) {
    float lse = M + __logf(S);
    float ptl = chlog[row] - lse;
    out[1 + row] = ptl;
    int b = row / 1023, t = row % 1023;
    float a = adv[b];
    float ratio = __expf(ptl - oldlp[row]);
    float l1 = ratio * a;
    float l2 = fminf(fmaxf(ratio, 0.8f), 1.3f) * a;
    float mk = (float)labels[b * 1024 + t + 1];
    atomicAdd(accum + 0, -fminf(l1, l2) * mk);
    atomicAdd(accum + 1, mk);
  }
}

__global__ void finalize_k(const float* __restrict__ accum, float* __restrict__ out) {
  out[0] = accum[0] / accum[1];
}

// ---------- launch ----------
extern "C" void kernel_launch(void* const* d_in, const int* in_sizes, int n_in,
                              void* d_out, int out_size, void* d_ws, size_t ws_size,
                              hipStream_t stream) {
  const float* hs     = (const float*)d_in[0];   // (4,1024,2048)
  const float* W      = (const float*)d_in[1];   // (2048,32768)
  const int*   ids    = (const int*)d_in[2];     // (4,1024)
  const int*   labels = (const int*)d_in[3];     // (4,1024)
  const float* adv    = (const float*)d_in[4];   // (4,)
  const float* oldlp  = (const float*)d_in[5];   // (4,1023)
  float* out = (float*)d_out;                    // [loss, 4092 x per_token_logps]

  char* ws = (char*)d_ws;
  u16*    WT       = (u16*)ws;                         // 134,217,728 B
  u16*    hb       = (u16*)(ws + 134217728);           //  16,777,216 B
  float2* partials = (float2*)(ws + 150994944);        //  16,777,216 B
  float*  chlog    = (float*)(ws + 167772160);         //      16,384 B
  int*    chosen   = (int*)(ws + 167788544);           //      16,384 B
  float*  accum    = (float*)(ws + 167804928);         //           8 B

  (void)hipFuncSetAttribute((const void*)gemm_lse,
                            hipFuncAttributeMaxDynamicSharedMemorySize, 131072);

  init_k<<<16, 256, 0, stream>>>(ids, chosen, accum);
  conv_h<<<8192, 256, 0, stream>>>(hs, hb);
  transpose_w<<<dim3(512, 32), 256, 0, stream>>>(W, WT);
  gemm_lse<<<2048, 512, 131072, stream>>>(hb, WT, chosen, partials, chlog);
  reduce_lse<<<1023, 256, 0, stream>>>(partials, chlog, oldlp, labels, adv, out, accum);
  finalize_k<<<1, 1, 0, stream>>>(accum, out);
}